// Round 10
// baseline (249.281 us; speedup 1.0000x reference)
//
#include <hip/hip_runtime.h>
#include <math.h>

// MS2D (VMamba SS2D) pipeline for MI355X.
// B=4, H=W=64, L=4096, DM=DI=96, N=16 states, K=4 directions, DTR=6.
// Chunked selective scan, NCH=128 chunks of LCH=32:
//   k_prep : An table + per-(k,d) structure flag (once)
//   scanA2 : local chunk scan. ROUND-10: full-n lanes (no nh split, no shfl),
//            explicit distance-1 prefetch + (192,3) bounds — r9 showed the
//            compiler allocated only 40 VGPR and serialized the loads.
//   scanB2 : parallel Hillis-Steele stitch over chunks -> h0 (in-place S)
//   scanY  : y = y_loc + C.(h0*exp(A*cumdelta)), LDS-staged h0, flag-driven
// Fallback (small ws): scanA_fb + scanB2(inline) + scanC_fb.

#define LQ 4096
#define NCH 128
#define LCH 32

__device__ __forceinline__ float sigmoid_f(float x){ return 1.0f/(1.0f + __expf(-x)); }
__device__ __forceinline__ float silu_f(float x){ return x * sigmoid_f(x); }
__device__ __forceinline__ float softplus_f(float x){ return (x > 20.0f) ? x : __logf(1.0f + __expf(x)); }

__device__ __forceinline__ int pos_of(int k, int i){
  switch(k & 3){
    case 0: return i;
    case 1: return ((i & 63) << 6) | (i >> 6);
    case 2: return LQ - 1 - i;
    default: { int j = LQ - 1 - i; return ((j & 63) << 6) | (j >> 6); }
  }
}

// half-powchain: e[j] = r^(j+1) for j<8, scaled by r^8 if nh==1. (fallback path)
__device__ __forceinline__ void pow8(float r, int nh, float* e){
  e[0]=r; e[1]=r*r; e[2]=e[1]*r; e[3]=e[1]*e[1];
  e[4]=e[3]*r; e[5]=e[3]*e[1]; e[6]=e[3]*e[2]; e[7]=e[3]*e[3];
  float m = nh ? e[7] : 1.0f;
  #pragma unroll
  for (int j=0;j<8;j++) e[j] *= m;
}

// full powchain: e[j] = r^(j+1), j<16; dependency depth 4.
__device__ __forceinline__ void pow16(float r, float* e){
  e[0]=r; e[1]=r*r; e[2]=e[1]*r; e[3]=e[1]*e[1];
  e[4]=e[3]*r; e[5]=e[3]*e[1]; e[6]=e[3]*e[2]; e[7]=e[3]*e[3];
  e[8]=e[7]*r; e[9]=e[7]*e[1]; e[10]=e[7]*e[2]; e[11]=e[7]*e[3];
  e[12]=e[7]*e[4]; e[13]=e[7]*e[5]; e[14]=e[7]*e[6]; e[15]=e[7]*e[7];
}

// ---------------- K0: precompute An table + structure flags ---------------
__global__ __launch_bounds__(64) void k_prep(const float* __restrict__ Alogs,
                                             float* __restrict__ An_tab,
                                             float* __restrict__ fflag){
  const int t = blockIdx.x*64 + threadIdx.x;    // (k*96+d) in [0,384)
  if (t >= 384) return;
  bool fast = true;
  #pragma unroll
  for (int n=0;n<16;n++){
    float An = -__expf(Alogs[t*16+n]);
    An_tab[t*16+n] = An;
    fast = fast && (fabsf(An + (float)(n+1)) < 1e-3f*(float)(n+1));
  }
  fflag[t] = fast ? 1.0f : 0.0f;
}

// ---------------- K1: in_proj GEMM (col-split): 512 blocks ----------------
__global__ __launch_bounds__(256) void k_inproj(const float* __restrict__ x,
                                                const float* __restrict__ wproj,
                                                float* __restrict__ xc,
                                                float* __restrict__ zb){
  __shared__ float a_s[64*97];
  __shared__ float w_s[96*97];
  const int t = threadIdx.x;
  const int row0 = (blockIdx.x >> 1) * 64;
  const int ch = blockIdx.x & 1;
  for (int e = t*4; e < 64*96; e += 1024){
    float4 v = *(const float4*)(x + (size_t)row0*96 + e);
    int r = e/96, c = e%96;
    float* p = a_s + r*97 + c;
    p[0]=v.x; p[1]=v.y; p[2]=v.z; p[3]=v.w;
  }
  for (int e = t*4; e < 96*96; e += 1024){
    float4 v = *(const float4*)(wproj + (size_t)ch*96*96 + e);
    int r = e/96, c = e%96;
    float* p = w_s + r*97 + c;
    p[0]=v.x; p[1]=v.y; p[2]=v.z; p[3]=v.w;
  }
  __syncthreads();
  const int tr = t >> 5, tc = t & 31;
  float acc[8][3];
  #pragma unroll
  for (int i=0;i<8;i++){
    #pragma unroll
    for (int j=0;j<3;j++) acc[i][j]=0.f;
  }
  for (int kk=0; kk<96; kk++){
    float a[8], b[3];
    #pragma unroll
    for (int i=0;i<8;i++) a[i] = a_s[(tr*8+i)*97+kk];
    #pragma unroll
    for (int j=0;j<3;j++) b[j] = w_s[(tc*3+j)*97+kk];
    #pragma unroll
    for (int i=0;i<8;i++){
      #pragma unroll
      for (int j=0;j<3;j++) acc[i][j] += a[i]*b[j];
    }
  }
  float* dst = ch ? zb : xc;
  #pragma unroll
  for (int i=0;i<8;i++){
    int row = row0 + tr*8 + i;
    #pragma unroll
    for (int j=0;j<3;j++) dst[(size_t)row*96 + tc*3 + j] = acc[i][j];
  }
}

// ---------------- K2: depthwise 3x3 conv + bias + SiLU ---------------------
__global__ __launch_bounds__(256) void k_conv(const float* __restrict__ xc,
                                              const float* __restrict__ cw,
                                              const float* __restrict__ cb,
                                              float* __restrict__ u){
  int e = blockIdx.x*256 + threadIdx.x;
  int d0 = (e % 24) * 4;
  int p = e / 24;                            // GLOBAL row (has batch offset)
  int w = p & 63, h = (p >> 6) & 63, b = p >> 12;
  float cwv[4][9];
  #pragma unroll
  for (int q=0;q<4;q++){
    #pragma unroll
    for (int tp=0;tp<9;tp++) cwv[q][tp] = cw[(d0+q)*9+tp];
  }
  float4 acc = make_float4(cb[d0], cb[d0+1], cb[d0+2], cb[d0+3]);
  #pragma unroll
  for (int kh=0; kh<3; kh++){
    int hh = h + kh - 1;
    if (hh < 0 || hh > 63) continue;
    #pragma unroll
    for (int kw=0; kw<3; kw++){
      int ww = w + kw - 1;
      if (ww < 0 || ww > 63) continue;
      float4 v = *(const float4*)(xc + ((size_t)((b<<12) + (hh<<6) + ww))*96 + d0);
      int tp = kh*3+kw;
      acc.x += v.x*cwv[0][tp]; acc.y += v.y*cwv[1][tp];
      acc.z += v.z*cwv[2][tp]; acc.w += v.w*cwv[3][tp];
    }
  }
  float4 o = make_float4(silu_f(acc.x), silu_f(acc.y), silu_f(acc.z), silu_f(acc.w));
  *(float4*)(u + (size_t)p*96 + d0) = o;
}

// ------- K3: x_proj per (b,k,scan-tile): emit dt/B/C (+us) scan-ordered ----
__global__ __launch_bounds__(128) void k_proj(const float* __restrict__ u,
                                              const float* __restrict__ xpw,
                                              float* __restrict__ dts,
                                              float* __restrict__ Bsb,
                                              float* __restrict__ Csb,
                                              float* __restrict__ us){
  __shared__ float u_s[64*97];
  __shared__ float w_s[40*97];
  const int t = threadIdx.x;
  const int blk = blockIdx.x;
  const int pt = blk & 63, k = (blk >> 6) & 3, b = blk >> 8;
  const int bk = b*4 + k;
  const int i0 = pt * 64;
  for (int e = t*4; e < 64*96; e += 512){
    int row = e/96, c = e%96;
    int p = pos_of(k, i0 + row);
    float4 v = *(const float4*)(u + ((size_t)((b<<12) + p))*96 + c);
    float* dst = u_s + row*97 + c;
    dst[0]=v.x; dst[1]=v.y; dst[2]=v.z; dst[3]=v.w;
    if (us) *(float4*)(us + ((size_t)((bk<<12) + i0 + row))*96 + c) = v;
  }
  for (int e = t*4; e < 40*96; e += 512){
    int r = e/96, c = e%96;
    float4 v = (r < 38) ? *(const float4*)(xpw + (k*38+r)*96 + c)
                        : make_float4(0,0,0,0);
    float* p = w_s + r*97 + c;
    p[0]=v.x; p[1]=v.y; p[2]=v.z; p[3]=v.w;
  }
  __syncthreads();
  const int posg = t & 15, cg = t >> 4;
  float acc[4][5];
  #pragma unroll
  for (int i=0;i<4;i++){
    #pragma unroll
    for (int j=0;j<5;j++) acc[i][j]=0.f;
  }
  for (int dd=0; dd<96; dd++){
    float uu[4], wv[5];
    #pragma unroll
    for (int i=0;i<4;i++) uu[i] = u_s[(posg*4+i)*97+dd];
    #pragma unroll
    for (int j=0;j<5;j++) wv[j] = w_s[(cg*5+j)*97+dd];
    #pragma unroll
    for (int i=0;i<4;i++){
      #pragma unroll
      for (int j=0;j<5;j++) acc[i][j] += uu[i]*wv[j];
    }
  }
  #pragma unroll
  for (int i=0;i<4;i++){
    int ii = i0 + posg*4 + i;
    int base = (bk<<12) + ii;
    #pragma unroll
    for (int j=0;j<5;j++){
      int c = cg*5 + j;
      float v = acc[i][j];
      if (c < 6)       dts[(size_t)base*6 + c] = v;
      else if (c < 22) Bsb[(size_t)base*16 + (c-6)] = v;
      else if (c < 38) Csb[(size_t)base*16 + (c-22)] = v;
    }
  }
}

// ------- K4 (primary): full-n lanes, distance-1 prefetch -------------------
// 1024 blocks x 192 threads = 2 chunks x 96 d; each lane owns all 16 states.
__global__ __launch_bounds__(192, 3) void k_scanA2(float* us,  // read u, write cumdelta
                                                const float* __restrict__ dts,
                                                const float* __restrict__ Bsb,
                                                const float* __restrict__ Csb,
                                                const float* __restrict__ dtw_g,
                                                const float* __restrict__ dtb_g,
                                                const float* __restrict__ An_tab,
                                                const float* __restrict__ fflag,
                                                float* __restrict__ S,
                                                float* __restrict__ sumd,
                                                float* __restrict__ ys){
  const int t = threadIdx.x;
  const int d = t % 96;
  const int c2 = t / 96;                 // 0..1
  const int blk = blockIdx.x;            // 16 bk x 64 groups
  const int bk = blk >> 6;
  const int k = bk & 3;
  const int chunk = ((blk & 63) << 1) | c2;
  const int ibase = chunk * LCH;
  const int kd = k*96 + d;
  int wfast = __all(fflag[kd] > 0.5f ? 1 : 0);
  float dtw[6];
  #pragma unroll
  for (int r=0;r<6;r++) dtw[r] = dtw_g[kd*6+r];
  const float bias = dtb_g[kd];
  float* usp = us + ((size_t)((bk<<12)+ibase))*96 + d;
  const float* dtp = dts + ((size_t)((bk<<12)+ibase))*6;
  const float4* Bp = (const float4*)(Bsb + ((size_t)((bk<<12)+ibase))*16);
  const float4* Cp = (const float4*)(Csb + ((size_t)((bk<<12)+ibase))*16);
  float* yp = ys + ((size_t)((bk<<12)+ibase))*96 + d;
  float h[16];
  #pragma unroll
  for (int n=0;n<16;n++) h[n]=0.f;
  float cum = 0.f;
  // prefetch step 0
  float u_n = usp[0];
  float2 q0n = *(const float2*)(dtp+0);
  float2 q1n = *(const float2*)(dtp+2);
  float2 q2n = *(const float2*)(dtp+4);
  float4 B0n=Bp[0], B1n=Bp[1], B2n=Bp[2], B3n=Bp[3];
  float4 C0n=Cp[0], C1n=Cp[1], C2n=Cp[2], C3n=Cp[3];
  if (wfast){
    #pragma unroll 4
    for (int il=0; il<LCH; il++){
      float u_c = u_n;
      float2 q0=q0n, q1=q1n, q2=q2n;
      float4 B0=B0n,B1=B1n,B2=B2n,B3=B3n;
      float4 C0=C0n,C1=C1n,C2=C2n,C3=C3n;
      int nx = (il+1 < LCH) ? il+1 : il;       // clamp: branch-free prefetch
      u_n = usp[(size_t)nx*96];
      q0n = *(const float2*)(dtp+nx*6);
      q1n = *(const float2*)(dtp+nx*6+2);
      q2n = *(const float2*)(dtp+nx*6+4);
      B0n=Bp[nx*4+0]; B1n=Bp[nx*4+1]; B2n=Bp[nx*4+2]; B3n=Bp[nx*4+3];
      C0n=Cp[nx*4+0]; C1n=Cp[nx*4+1]; C2n=Cp[nx*4+2]; C3n=Cp[nx*4+3];
      float accd = bias + dtw[0]*q0.x + dtw[1]*q0.y + dtw[2]*q1.x
                        + dtw[3]*q1.y + dtw[4]*q2.x + dtw[5]*q2.y;
      float t1 = __expf(accd);
      float r = 1.0f/(1.0f+t1);                // exp(-softplus)
      float delta = (accd > 20.f) ? accd : __logf(1.0f + t1);
      cum += delta;
      float du = delta * u_c;
      float Bv[16] = {B0.x,B0.y,B0.z,B0.w, B1.x,B1.y,B1.z,B1.w,
                      B2.x,B2.y,B2.z,B2.w, B3.x,B3.y,B3.z,B3.w};
      float Cv[16] = {C0.x,C0.y,C0.z,C0.w, C1.x,C1.y,C1.z,C1.w,
                      C2.x,C2.y,C2.z,C2.w, C3.x,C3.y,C3.z,C3.w};
      float e[16];
      pow16(r, e);
      float y = 0.f;
      #pragma unroll
      for (int n=0;n<16;n++){
        h[n] = h[n]*e[n] + du*Bv[n];
        y += h[n]*Cv[n];
      }
      yp[(size_t)il*96] = y;
      usp[(size_t)il*96] = cum;
    }
  } else {
    float An[16];
    #pragma unroll
    for (int n=0;n<16;n++) An[n] = An_tab[kd*16+n];
    #pragma unroll 2
    for (int il=0; il<LCH; il++){
      float u_c = u_n;
      float2 q0=q0n, q1=q1n, q2=q2n;
      float4 B0=B0n,B1=B1n,B2=B2n,B3=B3n;
      float4 C0=C0n,C1=C1n,C2=C2n,C3=C3n;
      int nx = (il+1 < LCH) ? il+1 : il;
      u_n = usp[(size_t)nx*96];
      q0n = *(const float2*)(dtp+nx*6);
      q1n = *(const float2*)(dtp+nx*6+2);
      q2n = *(const float2*)(dtp+nx*6+4);
      B0n=Bp[nx*4+0]; B1n=Bp[nx*4+1]; B2n=Bp[nx*4+2]; B3n=Bp[nx*4+3];
      C0n=Cp[nx*4+0]; C1n=Cp[nx*4+1]; C2n=Cp[nx*4+2]; C3n=Cp[nx*4+3];
      float accd = bias + dtw[0]*q0.x + dtw[1]*q0.y + dtw[2]*q1.x
                        + dtw[3]*q1.y + dtw[4]*q2.x + dtw[5]*q2.y;
      float delta = softplus_f(accd);
      cum += delta;
      float du = delta * u_c;
      float Bv[16] = {B0.x,B0.y,B0.z,B0.w, B1.x,B1.y,B1.z,B1.w,
                      B2.x,B2.y,B2.z,B2.w, B3.x,B3.y,B3.z,B3.w};
      float Cv[16] = {C0.x,C0.y,C0.z,C0.w, C1.x,C1.y,C1.z,C1.w,
                      C2.x,C2.y,C2.z,C2.w, C3.x,C3.y,C3.z,C3.w};
      float e[16];
      #pragma unroll
      for (int n=0;n<16;n++) e[n] = __expf(delta*An[n]);
      float y = 0.f;
      #pragma unroll
      for (int n=0;n<16;n++){
        h[n] = h[n]*e[n] + du*Bv[n];
        y += h[n]*Cv[n];
      }
      yp[(size_t)il*96] = y;
      usp[(size_t)il*96] = cum;
    }
  }
  const int sb = (bk*NCH + chunk)*96 + d;
  float4* Sp = (float4*)(S + (size_t)sb*16);
  Sp[0] = make_float4(h[0],h[1],h[2],h[3]);
  Sp[1] = make_float4(h[4],h[5],h[6],h[7]);
  Sp[2] = make_float4(h[8],h[9],h[10],h[11]);
  Sp[3] = make_float4(h[12],h[13],h[14],h[15]);
  sumd[sb] = cum;
}

// ------- K4 (fallback): local chunk scan, S/sumd only ----------------------
__global__ __launch_bounds__(384) void k_scanA_fb(const float* __restrict__ u,
                                                  const float* __restrict__ dts,
                                                  const float* __restrict__ Bsb,
                                                  const float* __restrict__ dtw_g,
                                                  const float* __restrict__ dtb_g,
                                                  const float* __restrict__ Alogs,
                                                  float* __restrict__ S,
                                                  float* __restrict__ sumd){
  const int t = threadIdx.x;
  const int c2 = t / 192;
  const int lane = t & 63;
  const int wv3 = (t % 192) >> 6;
  const int nh = (lane >> 5) & 1;
  const int d = wv3*32 + (lane & 31);
  const int blk = blockIdx.x;
  const int bk = blk >> 6;
  const int k = bk & 3, b = bk >> 2;
  const int chunk = ((blk & 63) << 1) | c2;
  const int ibase = chunk * LCH;
  float An[8];
  bool fast = true;
  #pragma unroll
  for (int j=0;j<8;j++){
    int n = nh*8 + j;
    An[j] = -__expf(Alogs[(k*96+d)*16+n]);
    fast = fast && (fabsf(An[j] + (float)(n+1)) < 1e-3f*(float)(n+1));
  }
  int wfast = __all(fast ? 1 : 0);
  float dtw[6];
  #pragma unroll
  for (int r=0;r<6;r++) dtw[r] = dtw_g[(k*96+d)*6+r];
  const float bias = dtb_g[k*96+d];
  int pb = pos_of(k, ibase);
  int pstep = pos_of(k, ibase+1) - pb;
  const float* uptr = u + ((size_t)((b<<12)+pb))*96 + d;
  const long ustep = (long)pstep*96;
  const float2* dtp = (const float2*)(dts + ((size_t)((bk<<12)+ibase))*6);
  const float4* Bp = (const float4*)(Bsb + ((size_t)((bk<<12)+ibase))*16) + nh*2;
  float h[8];
  #pragma unroll
  for (int n=0;n<8;n++) h[n]=0.f;
  float sdelta = 0.f;
  #pragma unroll 4
  for (int il=0; il<LCH; il++){
    float uv = *uptr;
    float2 q0 = dtp[0], q1 = dtp[1], q2 = dtp[2];
    float accd = bias + dtw[0]*q0.x + dtw[1]*q0.y + dtw[2]*q1.x
                      + dtw[3]*q1.y + dtw[4]*q2.x + dtw[5]*q2.y;
    float t1 = __expf(accd);
    float r = 1.0f / (1.0f + t1);
    float delta = (accd > 20.f) ? accd : __logf(1.0f + t1);
    sdelta += delta;
    float du = delta * uv;
    float4 b0 = Bp[0], b1 = Bp[1];
    float Bv[8] = {b0.x,b0.y,b0.z,b0.w, b1.x,b1.y,b1.z,b1.w};
    float e[8];
    if (wfast){ pow8(r, nh, e); }
    else {
      #pragma unroll
      for (int n=0;n<8;n++) e[n] = __expf(delta*An[n]);
    }
    #pragma unroll
    for (int n=0;n<8;n++) h[n] = h[n]*e[n] + du*Bv[n];
    uptr += ustep; dtp += 3; Bp += 4;
  }
  const int sb = (bk*NCH + chunk)*96 + d;
  float4* Sp = (float4*)(S + (size_t)sb*16 + nh*8);
  Sp[0] = make_float4(h[0],h[1],h[2],h[3]);
  Sp[1] = make_float4(h[4],h[5],h[6],h[7]);
  if (nh == 0) sumd[sb] = sdelta;
}

// ------- K5: parallel Hillis-Steele stitch over 128 chunks -----------------
__global__ __launch_bounds__(128) void k_scanB2(float* __restrict__ S,
                                                const float* __restrict__ sumd,
                                                const float* __restrict__ Alogs,
                                                const float* __restrict__ An_tab,
                                                const float* __restrict__ fflag){
  __shared__ float As[128*17];
  __shared__ float Bs[128*17];
  const int c = threadIdx.x;
  const int blk = blockIdx.x;           // bk*96 + d
  const int d = blk % 96;
  const int bk = blk / 96;
  const int k = bk & 3;
  const int sb = (bk*NCH + c)*96 + d;
  float a[16], bvals[16];
  {
    const float4* Sp = (const float4*)(S + (size_t)sb*16);
    float4 s0=Sp[0], s1=Sp[1], s2=Sp[2], s3=Sp[3];
    bvals[0]=s0.x;bvals[1]=s0.y;bvals[2]=s0.z;bvals[3]=s0.w;
    bvals[4]=s1.x;bvals[5]=s1.y;bvals[6]=s1.z;bvals[7]=s1.w;
    bvals[8]=s2.x;bvals[9]=s2.y;bvals[10]=s2.z;bvals[11]=s2.w;
    bvals[12]=s3.x;bvals[13]=s3.y;bvals[14]=s3.z;bvals[15]=s3.w;
  }
  const float sd = sumd[sb];
  bool fast;
  float An[16];
  if (An_tab){
    fast = fflag[k*96+d] > 0.5f;
    if (!fast){
      #pragma unroll
      for (int n=0;n<16;n++) An[n] = An_tab[(k*96+d)*16+n];
    }
  } else {
    fast = true;
    #pragma unroll
    for (int n=0;n<16;n++){
      An[n] = -__expf(Alogs[(k*96+d)*16+n]);
      fast = fast && (fabsf(An[n] + (float)(n+1)) < 1e-3f*(float)(n+1));
    }
  }
  if (fast){
    float q = __expf(-sd);
    float p = q;
    #pragma unroll
    for (int n=0;n<16;n++){ a[n] = p; p *= q; }
  } else {
    #pragma unroll
    for (int n=0;n<16;n++) a[n] = __expf(An[n]*sd);
  }
  #pragma unroll
  for (int n=0;n<16;n++){ As[c*17+n] = a[n]; Bs[c*17+n] = bvals[n]; }
  for (int dist=1; dist<128; dist<<=1){
    __syncthreads();
    float aL[16], bL[16];
    if (c >= dist){
      #pragma unroll
      for (int n=0;n<16;n++){ aL[n] = As[(c-dist)*17+n]; bL[n] = Bs[(c-dist)*17+n]; }
    }
    __syncthreads();
    if (c >= dist){
      #pragma unroll
      for (int n=0;n<16;n++){
        bvals[n] = bL[n]*a[n] + bvals[n];
        a[n] = aL[n]*a[n];
        As[c*17+n] = a[n]; Bs[c*17+n] = bvals[n];
      }
    }
  }
  __syncthreads();
  float h0[16];
  #pragma unroll
  for (int n=0;n<16;n++) h0[n] = (c == 0) ? 0.f : Bs[(c-1)*17+n];
  float4* Sp = (float4*)(S + (size_t)sb*16);
  Sp[0] = make_float4(h0[0],h0[1],h0[2],h0[3]);
  Sp[1] = make_float4(h0[4],h0[5],h0[6],h0[7]);
  Sp[2] = make_float4(h0[8],h0[9],h0[10],h0[11]);
  Sp[3] = make_float4(h0[12],h0[13],h0[14],h0[15]);
}

// ------- K6 (primary): y += C.(h0 * exp(A*cumdelta)), LDS-staged -----------
__global__ __launch_bounds__(256) void k_scanY(const float* __restrict__ us,  // cumdelta
                                               const float* __restrict__ Csb,
                                               const float* __restrict__ An_tab,
                                               const float* __restrict__ fflag,
                                               const float* __restrict__ h0buf,
                                               float* __restrict__ ys){
  __shared__ float h0_s[32*17];
  __shared__ float An_s[32*17];
  __shared__ float ff_s[32];
  const int t = threadIdx.x;
  const int blk = blockIdx.x;
  const int dslice = blk % 3;
  const int tmp = blk / 3;
  const int chunk = tmp & 127;
  const int bk = tmp >> 7;
  const int k = bk & 3;
  const int dbase = dslice * 32;
  {
    const float* h0src = h0buf + ((size_t)((bk*NCH + chunk)*96 + dbase))*16;
    const float* Ansrc = An_tab + (size_t)(k*96 + dbase)*16;
    for (int e = t; e < 512; e += 256){
      int dl = e >> 4, n = e & 15;
      h0_s[dl*17+n] = h0src[e];
      An_s[dl*17+n] = Ansrc[e];
    }
    if (t < 32) ff_s[t] = fflag[k*96 + dbase + t];
  }
  __syncthreads();
  const int il = t >> 3;
  const int dq = t & 7;
  const int d0 = dbase + dq*4;
  const int i = chunk*LCH + il;
  const size_t rowb = (size_t)((bk<<12) + i);
  float4 cd = *(const float4*)(us + rowb*96 + d0);
  float4 yl = *(const float4*)(ys + rowb*96 + d0);
  float Cv[16];
  {
    const float4* Cp = (const float4*)(Csb + rowb*16);
    float4 c0=Cp[0], c1=Cp[1], c2=Cp[2], c3=Cp[3];
    Cv[0]=c0.x;Cv[1]=c0.y;Cv[2]=c0.z;Cv[3]=c0.w;
    Cv[4]=c1.x;Cv[5]=c1.y;Cv[6]=c1.z;Cv[7]=c1.w;
    Cv[8]=c2.x;Cv[9]=c2.y;Cv[10]=c2.z;Cv[11]=c2.w;
    Cv[12]=c3.x;Cv[13]=c3.y;Cv[14]=c3.z;Cv[15]=c3.w;
  }
  float yout[4] = {yl.x, yl.y, yl.z, yl.w};
  float cdv[4] = {cd.x, cd.y, cd.z, cd.w};
  #pragma unroll
  for (int dd=0; dd<4; dd++){
    const int dl = dq*4 + dd;
    float acc = 0.f;
    if (ff_s[dl] > 0.5f){
      float q = __expf(-cdv[dd]);
      float p = q;
      #pragma unroll
      for (int n=0;n<16;n++){ acc += Cv[n]*h0_s[dl*17+n]*p; p *= q; }
    } else {
      #pragma unroll
      for (int n=0;n<16;n++) acc += Cv[n]*h0_s[dl*17+n]*__expf(An_s[dl*17+n]*cdv[dd]);
    }
    yout[dd] += acc;
  }
  *(float4*)(ys + rowb*96 + d0) = make_float4(yout[0], yout[1], yout[2], yout[3]);
}

// ------- K6 (fallback): rescan with true h0, y written scan-order ----------
__global__ __launch_bounds__(384) void k_scanC_fb(const float* __restrict__ u,
                                                  const float* __restrict__ dts,
                                                  const float* __restrict__ Bsb,
                                                  const float* __restrict__ Csb,
                                                  const float* __restrict__ dtw_g,
                                                  const float* __restrict__ dtb_g,
                                                  const float* __restrict__ Alogs,
                                                  const float* __restrict__ h0buf,
                                                  float* __restrict__ ys){
  const int t = threadIdx.x;
  const int c2 = t / 192;
  const int lane = t & 63;
  const int wv3 = (t % 192) >> 6;
  const int nh = (lane >> 5) & 1;
  const int d = wv3*32 + (lane & 31);
  const int blk = blockIdx.x;
  const int bk = blk >> 6;
  const int k = bk & 3, b = bk >> 2;
  const int chunk = ((blk & 63) << 1) | c2;
  const int ibase = chunk * LCH;
  float An[8];
  bool fast = true;
  #pragma unroll
  for (int j=0;j<8;j++){
    int n = nh*8 + j;
    An[j] = -__expf(Alogs[(k*96+d)*16+n]);
    fast = fast && (fabsf(An[j] + (float)(n+1)) < 1e-3f*(float)(n+1));
  }
  int wfast = __all(fast ? 1 : 0);
  float dtw[6];
  #pragma unroll
  for (int r=0;r<6;r++) dtw[r] = dtw_g[(k*96+d)*6+r];
  const float bias = dtb_g[k*96+d];
  int pb = pos_of(k, ibase);
  int pstep = pos_of(k, ibase+1) - pb;
  const float* uptr = u + ((size_t)((b<<12)+pb))*96 + d;
  const long ustep = (long)pstep*96;
  const float2* dtp = (const float2*)(dts + ((size_t)((bk<<12)+ibase))*6);
  const float4* Bp = (const float4*)(Bsb + ((size_t)((bk<<12)+ibase))*16) + nh*2;
  const float4* Cp = (const float4*)(Csb + ((size_t)((bk<<12)+ibase))*16) + nh*2;
  float* yp = ys + ((size_t)((bk<<12)+ibase))*96 + d;
  float h[8];
  const int sb = (bk*NCH + chunk)*96 + d;
  const float4* Hp = (const float4*)(h0buf + (size_t)sb*16 + nh*8);
  {
    float4 h0=Hp[0], h1=Hp[1];
    h[0]=h0.x;h[1]=h0.y;h[2]=h0.z;h[3]=h0.w;
    h[4]=h1.x;h[5]=h1.y;h[6]=h1.z;h[7]=h1.w;
  }
  #pragma unroll 4
  for (int il=0; il<LCH; il++){
    float uv = *uptr;
    float2 q0 = dtp[0], q1 = dtp[1], q2 = dtp[2];
    float accd = bias + dtw[0]*q0.x + dtw[1]*q0.y + dtw[2]*q1.x
                      + dtw[3]*q1.y + dtw[4]*q2.x + dtw[5]*q2.y;
    float t1 = __expf(accd);
    float r = 1.0f / (1.0f + t1);
    float delta = (accd > 20.f) ? accd : __logf(1.0f + t1);
    float du = delta * uv;
    float4 b0 = Bp[0], b1 = Bp[1];
    float4 c0 = Cp[0], c1 = Cp[1];
    float Bv[8] = {b0.x,b0.y,b0.z,b0.w, b1.x,b1.y,b1.z,b1.w};
    float Cv[8] = {c0.x,c0.y,c0.z,c0.w, c1.x,c1.y,c1.z,c1.w};
    float e[8];
    if (wfast){ pow8(r, nh, e); }
    else {
      #pragma unroll
      for (int n=0;n<8;n++) e[n] = __expf(delta*An[n]);
    }
    float y8 = 0.f;
    #pragma unroll
    for (int n=0;n<8;n++){
      h[n] = h[n]*e[n] + du*Bv[n];
      y8 += h[n]*Cv[n];
    }
    float y = y8 + __shfl_xor(y8, 32, 64);
    if (nh == 0) yp[(size_t)il*96] = y;
    uptr += ustep; dtp += 3; Bp += 4; Cp += 4;
  }
}

// ------- K7: gather 4 dirs (scan-order ys) + D*u + LN + gate + out_proj ----
__global__ __launch_bounds__(256) void k_out(const float* __restrict__ ys,
                                             const float* __restrict__ ubuf,
                                             const float* __restrict__ Dsg,
                                             const float* __restrict__ zbuf,
                                             const float* __restrict__ nw,
                                             const float* __restrict__ nb,
                                             const float* __restrict__ wout,
                                             float* __restrict__ out){
  __shared__ float w_s[96*97];
  __shared__ float g_s[32*97];
  const int t = threadIdx.x;
  const int b = blockIdx.x >> 7;
  const int pt = blockIdx.x & 127;
  const int p0 = pt * 32;
  for (int e=t*4; e<96*96; e+=1024){
    float4 v = *(const float4*)(wout+e);
    int r=e/96, c=e%96;
    float* p = w_s + r*97 + c;
    p[0]=v.x; p[1]=v.y; p[2]=v.z; p[3]=v.w;
  }
  const int pos = t >> 3, lane8 = t & 7, d0 = lane8*12;
  const int p = p0 + pos;
  const int tp = ((p & 63) << 6) | (p >> 6);
  int idx[4];
  idx[0] = p; idx[1] = tp; idx[2] = LQ-1-p; idx[3] = LQ-1-tp;
  float yv[12];
  float s1=0.f, s2=0.f;
  #pragma unroll
  for (int i=0;i<12;i+=4){
    float4 a = make_float4(0,0,0,0);
    #pragma unroll
    for (int kk=0;kk<4;kk++){
      float4 v = *(const float4*)(ys + ((size_t)(((b*4+kk)<<12) + idx[kk]))*96 + d0 + i);
      a.x+=v.x; a.y+=v.y; a.z+=v.z; a.w+=v.w;
    }
    float4 uv = *(const float4*)(ubuf + ((size_t)((b<<12)+p))*96 + d0 + i);
    #pragma unroll
    for (int q=0;q<4;q++){
      int dd = d0+i+q;
      float sD = Dsg[dd] + Dsg[96+dd] + Dsg[192+dd] + Dsg[288+dd];
      float uq = (q==0)?uv.x:(q==1)?uv.y:(q==2)?uv.z:uv.w;
      float* aq = (q==0)?&a.x:(q==1)?&a.y:(q==2)?&a.z:&a.w;
      *aq += sD * uq;
    }
    yv[i]=a.x; yv[i+1]=a.y; yv[i+2]=a.z; yv[i+3]=a.w;
    s1 += a.x+a.y+a.z+a.w;
    s2 += a.x*a.x + a.y*a.y + a.z*a.z + a.w*a.w;
  }
  #pragma unroll
  for (int m=1; m<8; m<<=1){
    s1 += __shfl_xor(s1, m, 64);
    s2 += __shfl_xor(s2, m, 64);
  }
  const float mu = s1 * (1.0f/96.0f);
  const float var = s2 * (1.0f/96.0f) - mu*mu;
  const float rstd = rsqrtf(var + 1e-5f);
  #pragma unroll
  for (int i=0;i<12;i+=4){
    float4 zv = *(const float4*)(zbuf + ((size_t)((b<<12)+p))*96 + d0 + i);
    float zz[4] = {zv.x,zv.y,zv.z,zv.w};
    #pragma unroll
    for (int q=0;q<4;q++){
      int d = d0+i+q;
      float yn = (yv[i+q]-mu)*rstd*nw[d] + nb[d];
      g_s[pos*97 + d] = yn * silu_f(zz[q]);
    }
  }
  __syncthreads();
  const int posg = t >> 5, mg = t & 31;
  float acc[4][3];
  #pragma unroll
  for (int i=0;i<4;i++){
    #pragma unroll
    for (int j=0;j<3;j++) acc[i][j]=0.f;
  }
  for (int dd=0; dd<96; dd++){
    float g4[4], w3[3];
    #pragma unroll
    for (int i=0;i<4;i++) g4[i] = g_s[(posg*4+i)*97+dd];
    #pragma unroll
    for (int j=0;j<3;j++) w3[j] = w_s[(mg*3+j)*97+dd];
    #pragma unroll
    for (int i=0;i<4;i++){
      #pragma unroll
      for (int j=0;j<3;j++) acc[i][j] += g4[i]*w3[j];
    }
  }
  #pragma unroll
  for (int i=0;i<4;i++){
    int prow = p0 + posg*4 + i;
    #pragma unroll
    for (int j=0;j<3;j++){
      out[((size_t)((b<<12)+prow))*96 + mg*3 + j] = acc[i][j];
    }
  }
}

extern "C" void kernel_launch(void* const* d_in, const int* in_sizes, int n_in,
                              void* d_out, int out_size, void* d_ws, size_t ws_size,
                              hipStream_t stream) {
  (void)in_sizes; (void)n_in; (void)out_size;
  const float* x   = (const float*)d_in[0];
  const float* ipw = (const float*)d_in[1];
  const float* cw  = (const float*)d_in[2];
  const float* cb  = (const float*)d_in[3];
  const float* xpw = (const float*)d_in[4];
  const float* dtw = (const float*)d_in[5];
  const float* dtb = (const float*)d_in[6];
  const float* alg = (const float*)d_in[7];
  const float* dsg = (const float*)d_in[8];
  const float* nw  = (const float*)d_in[9];
  const float* nb  = (const float*)d_in[10];
  const float* wo  = (const float*)d_in[11];
  float* out = (float*)d_out;

  // Core layout (floats), total 15,073,280 = 60.3 MB:
  float* w = (float*)d_ws;
  size_t off = 0;
  float* z_b    = w + off; off += 1572864;             // (B,L,96) z gate
  float* u_b    = w + off; off += 1572864;             // (B,L,96) conv+silu
  float* dts_b  = w + off; off += 393216;              // (B*K,L,6)  scan order
  float* Bs_b   = w + off; off += 1048576;             // (B*K,L,16) scan order
  float* Cs_b   = w + off; off += 1048576;             // (B*K,L,16) scan order
  float* Sh_b   = w + off; off += 3145728;             // (B*K,NCH,96,16) S then h0
  float* ys_b   = w + off; off += 6291456;             // (B*K,L,96) scan order
  float* xc_b   = ys_b;                                // alias: dead after conv
  // Primary extras: sumd (196,608) + us (6,291,456) + An_tab (6,144) + fflag (384)
  size_t need_primary = (off + 196608 + 6291456 + 6144 + 384) * sizeof(float); // 86.27MB
  float* sumd_ded = w + off;
  float* us_b     = sumd_ded + 196608;
  float* antab_b  = us_b + 6291456;
  float* fflag_b  = antab_b + 6144;
  bool primary = (ws_size >= need_primary);
  // Fallback sumd aliases ys start — safe: consumed by scanB2 before
  // scanC_fb writes ys.
  float* sumd_b = primary ? sumd_ded : ys_b;

  if (primary) k_prep<<<6, 64, 0, stream>>>(alg, antab_b, fflag_b);
  k_inproj<<<512, 256, 0, stream>>>(x, ipw, xc_b, z_b);
  k_conv  <<<1536, 256, 0, stream>>>(xc_b, cw, cb, u_b);
  k_proj  <<<1024, 128, 0, stream>>>(u_b, xpw, dts_b, Bs_b, Cs_b, primary ? us_b : nullptr);
  if (primary){
    k_scanA2<<<1024, 192, 0, stream>>>(us_b, dts_b, Bs_b, Cs_b, dtw, dtb,
                                       antab_b, fflag_b, Sh_b, sumd_b, ys_b);
    k_scanB2<<<1536, 128, 0, stream>>>(Sh_b, sumd_b, alg, antab_b, fflag_b);
    k_scanY <<<6144, 256, 0, stream>>>(us_b, Cs_b, antab_b, fflag_b, Sh_b, ys_b);
  } else {
    k_scanA_fb<<<1024, 384, 0, stream>>>(u_b, dts_b, Bs_b, dtw, dtb, alg, Sh_b, sumd_b);
    k_scanB2<<<1536, 128, 0, stream>>>(Sh_b, sumd_b, alg, nullptr, nullptr);
    k_scanC_fb<<<1024, 384, 0, stream>>>(u_b, dts_b, Bs_b, Cs_b, dtw, dtb, alg, Sh_b, ys_b);
  }
  k_out   <<<512, 256, 0, stream>>>(ys_b, u_b, dsg, z_b, nw, nb, wo, out);
}

// Round 11
// 230.585 us; speedup vs baseline: 1.0811x; 1.0811x over previous
//
#include <hip/hip_runtime.h>
#include <math.h>

// MS2D (VMamba SS2D) pipeline for MI355X.
// B=4, H=W=64, L=4096, DM=DI=96, N=16 states, K=4 directions, DTR=6.
// Chunked selective scan, NCH=128 chunks of LCH=32:
//   k_prep : An table + per-(k,d) structure flag (once)
//   scanA2 : local chunk scan, r9 nh-split layout (384 thr, 8 states/lane)
//            + distance-1 register prefetch. ROUND-10 LESSON: full-n (16
//            states) + prefetch spilled to scratch (+60 MB traffic) — keep
//            the prefetch working set at 8 states so it fits in VGPRs.
//            u read via affine gather (us u-copy dropped: k_proj -25 MB).
//   scanB2 : parallel Hillis-Steele stitch over chunks -> h0 (in-place S)
//   scanY  : y = y_loc + C.(h0*exp(A*cumdelta)), LDS-staged h0, flag-driven
// Fallback (small ws): scanA_fb + scanB2(inline) + scanC_fb.

#define LQ 4096
#define NCH 128
#define LCH 32

__device__ __forceinline__ float sigmoid_f(float x){ return 1.0f/(1.0f + __expf(-x)); }
__device__ __forceinline__ float silu_f(float x){ return x * sigmoid_f(x); }
__device__ __forceinline__ float softplus_f(float x){ return (x > 20.0f) ? x : __logf(1.0f + __expf(x)); }

__device__ __forceinline__ int pos_of(int k, int i){
  switch(k & 3){
    case 0: return i;
    case 1: return ((i & 63) << 6) | (i >> 6);
    case 2: return LQ - 1 - i;
    default: { int j = LQ - 1 - i; return ((j & 63) << 6) | (j >> 6); }
  }
}

// half-powchain: e[j] = r^(j+1) for j<8, scaled by r^8 if nh==1.
__device__ __forceinline__ void pow8(float r, int nh, float* e){
  e[0]=r; e[1]=r*r; e[2]=e[1]*r; e[3]=e[1]*e[1];
  e[4]=e[3]*r; e[5]=e[3]*e[1]; e[6]=e[3]*e[2]; e[7]=e[3]*e[3];
  float m = nh ? e[7] : 1.0f;
  #pragma unroll
  for (int j=0;j<8;j++) e[j] *= m;
}

// ---------------- K0: precompute An table + structure flags ---------------
__global__ __launch_bounds__(64) void k_prep(const float* __restrict__ Alogs,
                                             float* __restrict__ An_tab,
                                             float* __restrict__ fflag){
  const int t = blockIdx.x*64 + threadIdx.x;    // (k*96+d) in [0,384)
  if (t >= 384) return;
  bool fast = true;
  #pragma unroll
  for (int n=0;n<16;n++){
    float An = -__expf(Alogs[t*16+n]);
    An_tab[t*16+n] = An;
    fast = fast && (fabsf(An + (float)(n+1)) < 1e-3f*(float)(n+1));
  }
  fflag[t] = fast ? 1.0f : 0.0f;
}

// ---------------- K1: in_proj GEMM (col-split): 512 blocks ----------------
__global__ __launch_bounds__(256) void k_inproj(const float* __restrict__ x,
                                                const float* __restrict__ wproj,
                                                float* __restrict__ xc,
                                                float* __restrict__ zb){
  __shared__ float a_s[64*97];
  __shared__ float w_s[96*97];
  const int t = threadIdx.x;
  const int row0 = (blockIdx.x >> 1) * 64;
  const int ch = blockIdx.x & 1;
  for (int e = t*4; e < 64*96; e += 1024){
    float4 v = *(const float4*)(x + (size_t)row0*96 + e);
    int r = e/96, c = e%96;
    float* p = a_s + r*97 + c;
    p[0]=v.x; p[1]=v.y; p[2]=v.z; p[3]=v.w;
  }
  for (int e = t*4; e < 96*96; e += 1024){
    float4 v = *(const float4*)(wproj + (size_t)ch*96*96 + e);
    int r = e/96, c = e%96;
    float* p = w_s + r*97 + c;
    p[0]=v.x; p[1]=v.y; p[2]=v.z; p[3]=v.w;
  }
  __syncthreads();
  const int tr = t >> 5, tc = t & 31;
  float acc[8][3];
  #pragma unroll
  for (int i=0;i<8;i++){
    #pragma unroll
    for (int j=0;j<3;j++) acc[i][j]=0.f;
  }
  for (int kk=0; kk<96; kk++){
    float a[8], b[3];
    #pragma unroll
    for (int i=0;i<8;i++) a[i] = a_s[(tr*8+i)*97+kk];
    #pragma unroll
    for (int j=0;j<3;j++) b[j] = w_s[(tc*3+j)*97+kk];
    #pragma unroll
    for (int i=0;i<8;i++){
      #pragma unroll
      for (int j=0;j<3;j++) acc[i][j] += a[i]*b[j];
    }
  }
  float* dst = ch ? zb : xc;
  #pragma unroll
  for (int i=0;i<8;i++){
    int row = row0 + tr*8 + i;
    #pragma unroll
    for (int j=0;j<3;j++) dst[(size_t)row*96 + tc*3 + j] = acc[i][j];
  }
}

// ---------------- K2: depthwise 3x3 conv + bias + SiLU ---------------------
__global__ __launch_bounds__(256) void k_conv(const float* __restrict__ xc,
                                              const float* __restrict__ cw,
                                              const float* __restrict__ cb,
                                              float* __restrict__ u){
  int e = blockIdx.x*256 + threadIdx.x;
  int d0 = (e % 24) * 4;
  int p = e / 24;                            // GLOBAL row (has batch offset)
  int w = p & 63, h = (p >> 6) & 63, b = p >> 12;
  float cwv[4][9];
  #pragma unroll
  for (int q=0;q<4;q++){
    #pragma unroll
    for (int tp=0;tp<9;tp++) cwv[q][tp] = cw[(d0+q)*9+tp];
  }
  float4 acc = make_float4(cb[d0], cb[d0+1], cb[d0+2], cb[d0+3]);
  #pragma unroll
  for (int kh=0; kh<3; kh++){
    int hh = h + kh - 1;
    if (hh < 0 || hh > 63) continue;
    #pragma unroll
    for (int kw=0; kw<3; kw++){
      int ww = w + kw - 1;
      if (ww < 0 || ww > 63) continue;
      float4 v = *(const float4*)(xc + ((size_t)((b<<12) + (hh<<6) + ww))*96 + d0);
      int tp = kh*3+kw;
      acc.x += v.x*cwv[0][tp]; acc.y += v.y*cwv[1][tp];
      acc.z += v.z*cwv[2][tp]; acc.w += v.w*cwv[3][tp];
    }
  }
  float4 o = make_float4(silu_f(acc.x), silu_f(acc.y), silu_f(acc.z), silu_f(acc.w));
  *(float4*)(u + (size_t)p*96 + d0) = o;
}

// ------- K3: x_proj per (b,k,scan-tile): emit dt/B/C scan-ordered ----------
__global__ __launch_bounds__(128) void k_proj(const float* __restrict__ u,
                                              const float* __restrict__ xpw,
                                              float* __restrict__ dts,
                                              float* __restrict__ Bsb,
                                              float* __restrict__ Csb){
  __shared__ float u_s[64*97];
  __shared__ float w_s[40*97];
  const int t = threadIdx.x;
  const int blk = blockIdx.x;
  const int pt = blk & 63, k = (blk >> 6) & 3, b = blk >> 8;
  const int bk = b*4 + k;
  const int i0 = pt * 64;
  for (int e = t*4; e < 64*96; e += 512){
    int row = e/96, c = e%96;
    int p = pos_of(k, i0 + row);
    float4 v = *(const float4*)(u + ((size_t)((b<<12) + p))*96 + c);
    float* dst = u_s + row*97 + c;
    dst[0]=v.x; dst[1]=v.y; dst[2]=v.z; dst[3]=v.w;
  }
  for (int e = t*4; e < 40*96; e += 512){
    int r = e/96, c = e%96;
    float4 v = (r < 38) ? *(const float4*)(xpw + (k*38+r)*96 + c)
                        : make_float4(0,0,0,0);
    float* p = w_s + r*97 + c;
    p[0]=v.x; p[1]=v.y; p[2]=v.z; p[3]=v.w;
  }
  __syncthreads();
  const int posg = t & 15, cg = t >> 4;
  float acc[4][5];
  #pragma unroll
  for (int i=0;i<4;i++){
    #pragma unroll
    for (int j=0;j<5;j++) acc[i][j]=0.f;
  }
  for (int dd=0; dd<96; dd++){
    float uu[4], wv[5];
    #pragma unroll
    for (int i=0;i<4;i++) uu[i] = u_s[(posg*4+i)*97+dd];
    #pragma unroll
    for (int j=0;j<5;j++) wv[j] = w_s[(cg*5+j)*97+dd];
    #pragma unroll
    for (int i=0;i<4;i++){
      #pragma unroll
      for (int j=0;j<5;j++) acc[i][j] += uu[i]*wv[j];
    }
  }
  #pragma unroll
  for (int i=0;i<4;i++){
    int ii = i0 + posg*4 + i;
    int base = (bk<<12) + ii;
    #pragma unroll
    for (int j=0;j<5;j++){
      int c = cg*5 + j;
      float v = acc[i][j];
      if (c < 6)       dts[(size_t)base*6 + c] = v;
      else if (c < 22) Bsb[(size_t)base*16 + (c-6)] = v;
      else if (c < 38) Csb[(size_t)base*16 + (c-22)] = v;
    }
  }
}

// ------- K4 (primary): nh-split chunk scan + distance-1 prefetch -----------
// 1024 blocks x 384 thr = 2 chunks x 96 d x 2 n-halves (8 states/lane).
__global__ __launch_bounds__(384, 2) void k_scanA2(const float* __restrict__ u,
                                                const float* __restrict__ dts,
                                                const float* __restrict__ Bsb,
                                                const float* __restrict__ Csb,
                                                const float* __restrict__ dtw_g,
                                                const float* __restrict__ dtb_g,
                                                const float* __restrict__ An_tab,
                                                const float* __restrict__ fflag,
                                                float* __restrict__ S,
                                                float* __restrict__ sumd,
                                                float* __restrict__ ys,
                                                float* __restrict__ cum_g){
  const int t = threadIdx.x;
  const int c2 = t / 192;
  const int lane = t & 63;
  const int wv3 = (t % 192) >> 6;
  const int nh = (lane >> 5) & 1;
  const int d = wv3*32 + (lane & 31);
  const int blk = blockIdx.x;
  const int bk = blk >> 6;
  const int k = bk & 3, b = bk >> 2;
  const int chunk = ((blk & 63) << 1) | c2;
  const int ibase = chunk * LCH;
  const int kd = k*96 + d;
  int wfast = __all(fflag[kd] > 0.5f ? 1 : 0);
  float An[8];
  #pragma unroll
  for (int j=0;j<8;j++) An[j] = An_tab[kd*16 + nh*8 + j];
  float dtw[6];
  #pragma unroll
  for (int r=0;r<6;r++) dtw[r] = dtw_g[kd*6+r];
  const float bias = dtb_g[kd];
  // u via affine gather (each row read is 384 B contiguous)
  const int pb = pos_of(k, ibase);
  const int pstep = pos_of(k, ibase+1) - pb;
  const float* uptr = u + ((size_t)((b<<12)+pb))*96 + d;
  const long ustep = (long)pstep*96;
  const float2* dtp = (const float2*)(dts + ((size_t)((bk<<12)+ibase))*6);
  const float4* Bp = (const float4*)(Bsb + ((size_t)((bk<<12)+ibase))*16) + nh*2;
  const float4* Cp = (const float4*)(Csb + ((size_t)((bk<<12)+ibase))*16) + nh*2;
  float* yp = ys + ((size_t)((bk<<12)+ibase))*96 + d;
  float* cp = cum_g + ((size_t)((bk<<12)+ibase))*96 + d;
  float h[8];
  #pragma unroll
  for (int n=0;n<8;n++) h[n]=0.f;
  float cum = 0.f;
  // distance-1 prefetch (23 floats working set — fits VGPR, no spill)
  float u_n = uptr[0];
  float2 q0n = dtp[0], q1n = dtp[1], q2n = dtp[2];
  float4 B0n = Bp[0], B1n = Bp[1];
  float4 C0n = Cp[0], C1n = Cp[1];
  if (wfast){
    #pragma unroll 4
    for (int il=0; il<LCH; il++){
      float u_c = u_n;
      float2 q0=q0n, q1=q1n, q2=q2n;
      float4 B0=B0n, B1=B1n, C0=C0n, C1=C1n;
      const int nx = (il+1 < LCH) ? il+1 : il;
      u_n = uptr[(long)nx*ustep];
      q0n = dtp[nx*3+0]; q1n = dtp[nx*3+1]; q2n = dtp[nx*3+2];
      B0n = Bp[nx*4+0]; B1n = Bp[nx*4+1];
      C0n = Cp[nx*4+0]; C1n = Cp[nx*4+1];
      float accd = bias + dtw[0]*q0.x + dtw[1]*q0.y + dtw[2]*q1.x
                        + dtw[3]*q1.y + dtw[4]*q2.x + dtw[5]*q2.y;
      float t1 = __expf(accd);
      float r = 1.0f/(1.0f+t1);                // exp(-softplus)
      float delta = (accd > 20.f) ? accd : __logf(1.0f + t1);
      cum += delta;
      float du = delta * u_c;
      float Bv[8] = {B0.x,B0.y,B0.z,B0.w, B1.x,B1.y,B1.z,B1.w};
      float Cv[8] = {C0.x,C0.y,C0.z,C0.w, C1.x,C1.y,C1.z,C1.w};
      float e[8];
      pow8(r, nh, e);
      float y8 = 0.f;
      #pragma unroll
      for (int n=0;n<8;n++){
        h[n] = h[n]*e[n] + du*Bv[n];
        y8 += h[n]*Cv[n];
      }
      float y = y8 + __shfl_xor(y8, 32, 64);
      if (nh == 0){ yp[(size_t)il*96] = y; cp[(size_t)il*96] = cum; }
    }
  } else {
    #pragma unroll 2
    for (int il=0; il<LCH; il++){
      float u_c = u_n;
      float2 q0=q0n, q1=q1n, q2=q2n;
      float4 B0=B0n, B1=B1n, C0=C0n, C1=C1n;
      const int nx = (il+1 < LCH) ? il+1 : il;
      u_n = uptr[(long)nx*ustep];
      q0n = dtp[nx*3+0]; q1n = dtp[nx*3+1]; q2n = dtp[nx*3+2];
      B0n = Bp[nx*4+0]; B1n = Bp[nx*4+1];
      C0n = Cp[nx*4+0]; C1n = Cp[nx*4+1];
      float accd = bias + dtw[0]*q0.x + dtw[1]*q0.y + dtw[2]*q1.x
                        + dtw[3]*q1.y + dtw[4]*q2.x + dtw[5]*q2.y;
      float delta = softplus_f(accd);
      cum += delta;
      float du = delta * u_c;
      float Bv[8] = {B0.x,B0.y,B0.z,B0.w, B1.x,B1.y,B1.z,B1.w};
      float Cv[8] = {C0.x,C0.y,C0.z,C0.w, C1.x,C1.y,C1.z,C1.w};
      float e[8];
      #pragma unroll
      for (int n=0;n<8;n++) e[n] = __expf(delta*An[n]);
      float y8 = 0.f;
      #pragma unroll
      for (int n=0;n<8;n++){
        h[n] = h[n]*e[n] + du*Bv[n];
        y8 += h[n]*Cv[n];
      }
      float y = y8 + __shfl_xor(y8, 32, 64);
      if (nh == 0){ yp[(size_t)il*96] = y; cp[(size_t)il*96] = cum; }
    }
  }
  const int sb = (bk*NCH + chunk)*96 + d;
  float4* Sp = (float4*)(S + (size_t)sb*16 + nh*8);
  Sp[0] = make_float4(h[0],h[1],h[2],h[3]);
  Sp[1] = make_float4(h[4],h[5],h[6],h[7]);
  if (nh == 0) sumd[sb] = cum;
}

// ------- K4 (fallback): local chunk scan, S/sumd only ----------------------
__global__ __launch_bounds__(384) void k_scanA_fb(const float* __restrict__ u,
                                                  const float* __restrict__ dts,
                                                  const float* __restrict__ Bsb,
                                                  const float* __restrict__ dtw_g,
                                                  const float* __restrict__ dtb_g,
                                                  const float* __restrict__ Alogs,
                                                  float* __restrict__ S,
                                                  float* __restrict__ sumd){
  const int t = threadIdx.x;
  const int c2 = t / 192;
  const int lane = t & 63;
  const int wv3 = (t % 192) >> 6;
  const int nh = (lane >> 5) & 1;
  const int d = wv3*32 + (lane & 31);
  const int blk = blockIdx.x;
  const int bk = blk >> 6;
  const int k = bk & 3, b = bk >> 2;
  const int chunk = ((blk & 63) << 1) | c2;
  const int ibase = chunk * LCH;
  float An[8];
  bool fast = true;
  #pragma unroll
  for (int j=0;j<8;j++){
    int n = nh*8 + j;
    An[j] = -__expf(Alogs[(k*96+d)*16+n]);
    fast = fast && (fabsf(An[j] + (float)(n+1)) < 1e-3f*(float)(n+1));
  }
  int wfast = __all(fast ? 1 : 0);
  float dtw[6];
  #pragma unroll
  for (int r=0;r<6;r++) dtw[r] = dtw_g[(k*96+d)*6+r];
  const float bias = dtb_g[k*96+d];
  int pb = pos_of(k, ibase);
  int pstep = pos_of(k, ibase+1) - pb;
  const float* uptr = u + ((size_t)((b<<12)+pb))*96 + d;
  const long ustep = (long)pstep*96;
  const float2* dtp = (const float2*)(dts + ((size_t)((bk<<12)+ibase))*6);
  const float4* Bp = (const float4*)(Bsb + ((size_t)((bk<<12)+ibase))*16) + nh*2;
  float h[8];
  #pragma unroll
  for (int n=0;n<8;n++) h[n]=0.f;
  float sdelta = 0.f;
  #pragma unroll 4
  for (int il=0; il<LCH; il++){
    float uv = *uptr;
    float2 q0 = dtp[0], q1 = dtp[1], q2 = dtp[2];
    float accd = bias + dtw[0]*q0.x + dtw[1]*q0.y + dtw[2]*q1.x
                      + dtw[3]*q1.y + dtw[4]*q2.x + dtw[5]*q2.y;
    float t1 = __expf(accd);
    float r = 1.0f / (1.0f + t1);
    float delta = (accd > 20.f) ? accd : __logf(1.0f + t1);
    sdelta += delta;
    float du = delta * uv;
    float4 b0 = Bp[0], b1 = Bp[1];
    float Bv[8] = {b0.x,b0.y,b0.z,b0.w, b1.x,b1.y,b1.z,b1.w};
    float e[8];
    if (wfast){ pow8(r, nh, e); }
    else {
      #pragma unroll
      for (int n=0;n<8;n++) e[n] = __expf(delta*An[n]);
    }
    #pragma unroll
    for (int n=0;n<8;n++) h[n] = h[n]*e[n] + du*Bv[n];
    uptr += ustep; dtp += 3; Bp += 4;
  }
  const int sb = (bk*NCH + chunk)*96 + d;
  float4* Sp = (float4*)(S + (size_t)sb*16 + nh*8);
  Sp[0] = make_float4(h[0],h[1],h[2],h[3]);
  Sp[1] = make_float4(h[4],h[5],h[6],h[7]);
  if (nh == 0) sumd[sb] = sdelta;
}

// ------- K5: parallel Hillis-Steele stitch over 128 chunks -----------------
__global__ __launch_bounds__(128) void k_scanB2(float* __restrict__ S,
                                                const float* __restrict__ sumd,
                                                const float* __restrict__ Alogs,
                                                const float* __restrict__ An_tab,
                                                const float* __restrict__ fflag){
  __shared__ float As[128*17];
  __shared__ float Bs[128*17];
  const int c = threadIdx.x;
  const int blk = blockIdx.x;           // bk*96 + d
  const int d = blk % 96;
  const int bk = blk / 96;
  const int k = bk & 3;
  const int sb = (bk*NCH + c)*96 + d;
  float a[16], bvals[16];
  {
    const float4* Sp = (const float4*)(S + (size_t)sb*16);
    float4 s0=Sp[0], s1=Sp[1], s2=Sp[2], s3=Sp[3];
    bvals[0]=s0.x;bvals[1]=s0.y;bvals[2]=s0.z;bvals[3]=s0.w;
    bvals[4]=s1.x;bvals[5]=s1.y;bvals[6]=s1.z;bvals[7]=s1.w;
    bvals[8]=s2.x;bvals[9]=s2.y;bvals[10]=s2.z;bvals[11]=s2.w;
    bvals[12]=s3.x;bvals[13]=s3.y;bvals[14]=s3.z;bvals[15]=s3.w;
  }
  const float sd = sumd[sb];
  bool fast;
  float An[16];
  if (An_tab){
    fast = fflag[k*96+d] > 0.5f;
    if (!fast){
      #pragma unroll
      for (int n=0;n<16;n++) An[n] = An_tab[(k*96+d)*16+n];
    }
  } else {
    fast = true;
    #pragma unroll
    for (int n=0;n<16;n++){
      An[n] = -__expf(Alogs[(k*96+d)*16+n]);
      fast = fast && (fabsf(An[n] + (float)(n+1)) < 1e-3f*(float)(n+1));
    }
  }
  if (fast){
    float q = __expf(-sd);
    float p = q;
    #pragma unroll
    for (int n=0;n<16;n++){ a[n] = p; p *= q; }
  } else {
    #pragma unroll
    for (int n=0;n<16;n++) a[n] = __expf(An[n]*sd);
  }
  #pragma unroll
  for (int n=0;n<16;n++){ As[c*17+n] = a[n]; Bs[c*17+n] = bvals[n]; }
  for (int dist=1; dist<128; dist<<=1){
    __syncthreads();
    float aL[16], bL[16];
    if (c >= dist){
      #pragma unroll
      for (int n=0;n<16;n++){ aL[n] = As[(c-dist)*17+n]; bL[n] = Bs[(c-dist)*17+n]; }
    }
    __syncthreads();
    if (c >= dist){
      #pragma unroll
      for (int n=0;n<16;n++){
        bvals[n] = bL[n]*a[n] + bvals[n];
        a[n] = aL[n]*a[n];
        As[c*17+n] = a[n]; Bs[c*17+n] = bvals[n];
      }
    }
  }
  __syncthreads();
  float h0[16];
  #pragma unroll
  for (int n=0;n<16;n++) h0[n] = (c == 0) ? 0.f : Bs[(c-1)*17+n];
  float4* Sp = (float4*)(S + (size_t)sb*16);
  Sp[0] = make_float4(h0[0],h0[1],h0[2],h0[3]);
  Sp[1] = make_float4(h0[4],h0[5],h0[6],h0[7]);
  Sp[2] = make_float4(h0[8],h0[9],h0[10],h0[11]);
  Sp[3] = make_float4(h0[12],h0[13],h0[14],h0[15]);
}

// ------- K6 (primary): y += C.(h0 * exp(A*cumdelta)), LDS-staged -----------
__global__ __launch_bounds__(256) void k_scanY(const float* __restrict__ cum_g,
                                               const float* __restrict__ Csb,
                                               const float* __restrict__ An_tab,
                                               const float* __restrict__ fflag,
                                               const float* __restrict__ h0buf,
                                               float* __restrict__ ys){
  __shared__ float h0_s[32*17];
  __shared__ float An_s[32*17];
  __shared__ float ff_s[32];
  const int t = threadIdx.x;
  const int blk = blockIdx.x;
  const int dslice = blk % 3;
  const int tmp = blk / 3;
  const int chunk = tmp & 127;
  const int bk = tmp >> 7;
  const int k = bk & 3;
  const int dbase = dslice * 32;
  {
    const float* h0src = h0buf + ((size_t)((bk*NCH + chunk)*96 + dbase))*16;
    const float* Ansrc = An_tab + (size_t)(k*96 + dbase)*16;
    for (int e = t; e < 512; e += 256){
      int dl = e >> 4, n = e & 15;
      h0_s[dl*17+n] = h0src[e];
      An_s[dl*17+n] = Ansrc[e];
    }
    if (t < 32) ff_s[t] = fflag[k*96 + dbase + t];
  }
  __syncthreads();
  const int il = t >> 3;
  const int dq = t & 7;
  const int d0 = dbase + dq*4;
  const int i = chunk*LCH + il;
  const size_t rowb = (size_t)((bk<<12) + i);
  float4 cd = *(const float4*)(cum_g + rowb*96 + d0);
  float4 yl = *(const float4*)(ys + rowb*96 + d0);
  float Cv[16];
  {
    const float4* Cp = (const float4*)(Csb + rowb*16);
    float4 c0=Cp[0], c1=Cp[1], c2=Cp[2], c3=Cp[3];
    Cv[0]=c0.x;Cv[1]=c0.y;Cv[2]=c0.z;Cv[3]=c0.w;
    Cv[4]=c1.x;Cv[5]=c1.y;Cv[6]=c1.z;Cv[7]=c1.w;
    Cv[8]=c2.x;Cv[9]=c2.y;Cv[10]=c2.z;Cv[11]=c2.w;
    Cv[12]=c3.x;Cv[13]=c3.y;Cv[14]=c3.z;Cv[15]=c3.w;
  }
  float yout[4] = {yl.x, yl.y, yl.z, yl.w};
  float cdv[4] = {cd.x, cd.y, cd.z, cd.w};
  #pragma unroll
  for (int dd=0; dd<4; dd++){
    const int dl = dq*4 + dd;
    float acc = 0.f;
    if (ff_s[dl] > 0.5f){
      float q = __expf(-cdv[dd]);
      float p = q;
      #pragma unroll
      for (int n=0;n<16;n++){ acc += Cv[n]*h0_s[dl*17+n]*p; p *= q; }
    } else {
      #pragma unroll
      for (int n=0;n<16;n++) acc += Cv[n]*h0_s[dl*17+n]*__expf(An_s[dl*17+n]*cdv[dd]);
    }
    yout[dd] += acc;
  }
  *(float4*)(ys + rowb*96 + d0) = make_float4(yout[0], yout[1], yout[2], yout[3]);
}

// ------- K6 (fallback): rescan with true h0, y written scan-order ----------
__global__ __launch_bounds__(384) void k_scanC_fb(const float* __restrict__ u,
                                                  const float* __restrict__ dts,
                                                  const float* __restrict__ Bsb,
                                                  const float* __restrict__ Csb,
                                                  const float* __restrict__ dtw_g,
                                                  const float* __restrict__ dtb_g,
                                                  const float* __restrict__ Alogs,
                                                  const float* __restrict__ h0buf,
                                                  float* __restrict__ ys){
  const int t = threadIdx.x;
  const int c2 = t / 192;
  const int lane = t & 63;
  const int wv3 = (t % 192) >> 6;
  const int nh = (lane >> 5) & 1;
  const int d = wv3*32 + (lane & 31);
  const int blk = blockIdx.x;
  const int bk = blk >> 6;
  const int k = bk & 3, b = bk >> 2;
  const int chunk = ((blk & 63) << 1) | c2;
  const int ibase = chunk * LCH;
  float An[8];
  bool fast = true;
  #pragma unroll
  for (int j=0;j<8;j++){
    int n = nh*8 + j;
    An[j] = -__expf(Alogs[(k*96+d)*16+n]);
    fast = fast && (fabsf(An[j] + (float)(n+1)) < 1e-3f*(float)(n+1));
  }
  int wfast = __all(fast ? 1 : 0);
  float dtw[6];
  #pragma unroll
  for (int r=0;r<6;r++) dtw[r] = dtw_g[(k*96+d)*6+r];
  const float bias = dtb_g[k*96+d];
  int pb = pos_of(k, ibase);
  int pstep = pos_of(k, ibase+1) - pb;
  const float* uptr = u + ((size_t)((b<<12)+pb))*96 + d;
  const long ustep = (long)pstep*96;
  const float2* dtp = (const float2*)(dts + ((size_t)((bk<<12)+ibase))*6);
  const float4* Bp = (const float4*)(Bsb + ((size_t)((bk<<12)+ibase))*16) + nh*2;
  const float4* Cp = (const float4*)(Csb + ((size_t)((bk<<12)+ibase))*16) + nh*2;
  float* yp = ys + ((size_t)((bk<<12)+ibase))*96 + d;
  float h[8];
  const int sb = (bk*NCH + chunk)*96 + d;
  const float4* Hp = (const float4*)(h0buf + (size_t)sb*16 + nh*8);
  {
    float4 h0=Hp[0], h1=Hp[1];
    h[0]=h0.x;h[1]=h0.y;h[2]=h0.z;h[3]=h0.w;
    h[4]=h1.x;h[5]=h1.y;h[6]=h1.z;h[7]=h1.w;
  }
  #pragma unroll 4
  for (int il=0; il<LCH; il++){
    float uv = *uptr;
    float2 q0 = dtp[0], q1 = dtp[1], q2 = dtp[2];
    float accd = bias + dtw[0]*q0.x + dtw[1]*q0.y + dtw[2]*q1.x
                      + dtw[3]*q1.y + dtw[4]*q2.x + dtw[5]*q2.y;
    float t1 = __expf(accd);
    float r = 1.0f / (1.0f + t1);
    float delta = (accd > 20.f) ? accd : __logf(1.0f + t1);
    float du = delta * uv;
    float4 b0 = Bp[0], b1 = Bp[1];
    float4 c0 = Cp[0], c1 = Cp[1];
    float Bv[8] = {b0.x,b0.y,b0.z,b0.w, b1.x,b1.y,b1.z,b1.w};
    float Cv[8] = {c0.x,c0.y,c0.z,c0.w, c1.x,c1.y,c1.z,c1.w};
    float e[8];
    if (wfast){ pow8(r, nh, e); }
    else {
      #pragma unroll
      for (int n=0;n<8;n++) e[n] = __expf(delta*An[n]);
    }
    float y8 = 0.f;
    #pragma unroll
    for (int n=0;n<8;n++){
      h[n] = h[n]*e[n] + du*Bv[n];
      y8 += h[n]*Cv[n];
    }
    float y = y8 + __shfl_xor(y8, 32, 64);
    if (nh == 0) yp[(size_t)il*96] = y;
    uptr += ustep; dtp += 3; Bp += 4; Cp += 4;
  }
}

// ------- K7: gather 4 dirs (scan-order ys) + D*u + LN + gate + out_proj ----
__global__ __launch_bounds__(256) void k_out(const float* __restrict__ ys,
                                             const float* __restrict__ ubuf,
                                             const float* __restrict__ Dsg,
                                             const float* __restrict__ zbuf,
                                             const float* __restrict__ nw,
                                             const float* __restrict__ nb,
                                             const float* __restrict__ wout,
                                             float* __restrict__ out){
  __shared__ float w_s[96*97];
  __shared__ float g_s[32*97];
  const int t = threadIdx.x;
  const int b = blockIdx.x >> 7;
  const int pt = blockIdx.x & 127;
  const int p0 = pt * 32;
  for (int e=t*4; e<96*96; e+=1024){
    float4 v = *(const float4*)(wout+e);
    int r=e/96, c=e%96;
    float* p = w_s + r*97 + c;
    p[0]=v.x; p[1]=v.y; p[2]=v.z; p[3]=v.w;
  }
  const int pos = t >> 3, lane8 = t & 7, d0 = lane8*12;
  const int p = p0 + pos;
  const int tp = ((p & 63) << 6) | (p >> 6);
  int idx[4];
  idx[0] = p; idx[1] = tp; idx[2] = LQ-1-p; idx[3] = LQ-1-tp;
  float yv[12];
  float s1=0.f, s2=0.f;
  #pragma unroll
  for (int i=0;i<12;i+=4){
    float4 a = make_float4(0,0,0,0);
    #pragma unroll
    for (int kk=0;kk<4;kk++){
      float4 v = *(const float4*)(ys + ((size_t)(((b*4+kk)<<12) + idx[kk]))*96 + d0 + i);
      a.x+=v.x; a.y+=v.y; a.z+=v.z; a.w+=v.w;
    }
    float4 uv = *(const float4*)(ubuf + ((size_t)((b<<12)+p))*96 + d0 + i);
    #pragma unroll
    for (int q=0;q<4;q++){
      int dd = d0+i+q;
      float sD = Dsg[dd] + Dsg[96+dd] + Dsg[192+dd] + Dsg[288+dd];
      float uq = (q==0)?uv.x:(q==1)?uv.y:(q==2)?uv.z:uv.w;
      float* aq = (q==0)?&a.x:(q==1)?&a.y:(q==2)?&a.z:&a.w;
      *aq += sD * uq;
    }
    yv[i]=a.x; yv[i+1]=a.y; yv[i+2]=a.z; yv[i+3]=a.w;
    s1 += a.x+a.y+a.z+a.w;
    s2 += a.x*a.x + a.y*a.y + a.z*a.z + a.w*a.w;
  }
  #pragma unroll
  for (int m=1; m<8; m<<=1){
    s1 += __shfl_xor(s1, m, 64);
    s2 += __shfl_xor(s2, m, 64);
  }
  const float mu = s1 * (1.0f/96.0f);
  const float var = s2 * (1.0f/96.0f) - mu*mu;
  const float rstd = rsqrtf(var + 1e-5f);
  #pragma unroll
  for (int i=0;i<12;i+=4){
    float4 zv = *(const float4*)(zbuf + ((size_t)((b<<12)+p))*96 + d0 + i);
    float zz[4] = {zv.x,zv.y,zv.z,zv.w};
    #pragma unroll
    for (int q=0;q<4;q++){
      int d = d0+i+q;
      float yn = (yv[i+q]-mu)*rstd*nw[d] + nb[d];
      g_s[pos*97 + d] = yn * silu_f(zz[q]);
    }
  }
  __syncthreads();
  const int posg = t >> 5, mg = t & 31;
  float acc[4][3];
  #pragma unroll
  for (int i=0;i<4;i++){
    #pragma unroll
    for (int j=0;j<3;j++) acc[i][j]=0.f;
  }
  for (int dd=0; dd<96; dd++){
    float g4[4], w3[3];
    #pragma unroll
    for (int i=0;i<4;i++) g4[i] = g_s[(posg*4+i)*97+dd];
    #pragma unroll
    for (int j=0;j<3;j++) w3[j] = w_s[(mg*3+j)*97+dd];
    #pragma unroll
    for (int i=0;i<4;i++){
      #pragma unroll
      for (int j=0;j<3;j++) acc[i][j] += g4[i]*w3[j];
    }
  }
  #pragma unroll
  for (int i=0;i<4;i++){
    int prow = p0 + posg*4 + i;
    #pragma unroll
    for (int j=0;j<3;j++){
      out[((size_t)((b<<12)+prow))*96 + mg*3 + j] = acc[i][j];
    }
  }
}

extern "C" void kernel_launch(void* const* d_in, const int* in_sizes, int n_in,
                              void* d_out, int out_size, void* d_ws, size_t ws_size,
                              hipStream_t stream) {
  (void)in_sizes; (void)n_in; (void)out_size;
  const float* x   = (const float*)d_in[0];
  const float* ipw = (const float*)d_in[1];
  const float* cw  = (const float*)d_in[2];
  const float* cb  = (const float*)d_in[3];
  const float* xpw = (const float*)d_in[4];
  const float* dtw = (const float*)d_in[5];
  const float* dtb = (const float*)d_in[6];
  const float* alg = (const float*)d_in[7];
  const float* dsg = (const float*)d_in[8];
  const float* nw  = (const float*)d_in[9];
  const float* nb  = (const float*)d_in[10];
  const float* wo  = (const float*)d_in[11];
  float* out = (float*)d_out;

  // Core layout (floats), total 15,073,280 = 60.3 MB:
  float* w = (float*)d_ws;
  size_t off = 0;
  float* z_b    = w + off; off += 1572864;             // (B,L,96) z gate
  float* u_b    = w + off; off += 1572864;             // (B,L,96) conv+silu
  float* dts_b  = w + off; off += 393216;              // (B*K,L,6)  scan order
  float* Bs_b   = w + off; off += 1048576;             // (B*K,L,16) scan order
  float* Cs_b   = w + off; off += 1048576;             // (B*K,L,16) scan order
  float* Sh_b   = w + off; off += 3145728;             // (B*K,NCH,96,16) S then h0
  float* ys_b   = w + off; off += 6291456;             // (B*K,L,96) scan order
  float* xc_b   = ys_b;                                // alias: dead after conv
  // Primary extras: sumd (196,608) + cum (6,291,456) + An_tab (6,144) + fflag (384)
  size_t need_primary = (off + 196608 + 6291456 + 6144 + 384) * sizeof(float); // 86.27MB
  float* sumd_ded = w + off;
  float* cum_b    = sumd_ded + 196608;
  float* antab_b  = cum_b + 6291456;
  float* fflag_b  = antab_b + 6144;
  bool primary = (ws_size >= need_primary);
  // Fallback sumd aliases ys start — safe: consumed by scanB2 before
  // scanC_fb writes ys.
  float* sumd_b = primary ? sumd_ded : ys_b;

  if (primary) k_prep<<<6, 64, 0, stream>>>(alg, antab_b, fflag_b);
  k_inproj<<<512, 256, 0, stream>>>(x, ipw, xc_b, z_b);
  k_conv  <<<1536, 256, 0, stream>>>(xc_b, cw, cb, u_b);
  k_proj  <<<1024, 128, 0, stream>>>(u_b, xpw, dts_b, Bs_b, Cs_b);
  if (primary){
    k_scanA2<<<1024, 384, 0, stream>>>(u_b, dts_b, Bs_b, Cs_b, dtw, dtb,
                                       antab_b, fflag_b, Sh_b, sumd_b, ys_b, cum_b);
    k_scanB2<<<1536, 128, 0, stream>>>(Sh_b, sumd_b, alg, antab_b, fflag_b);
    k_scanY <<<6144, 256, 0, stream>>>(cum_b, Cs_b, antab_b, fflag_b, Sh_b, ys_b);
  } else {
    k_scanA_fb<<<1024, 384, 0, stream>>>(u_b, dts_b, Bs_b, dtw, dtb, alg, Sh_b, sumd_b);
    k_scanB2<<<1536, 128, 0, stream>>>(Sh_b, sumd_b, alg, nullptr, nullptr);
    k_scanC_fb<<<1024, 384, 0, stream>>>(u_b, dts_b, Bs_b, Cs_b, dtw, dtb, alg, Sh_b, ys_b);
  }
  k_out   <<<512, 256, 0, stream>>>(ys_b, u_b, dsg, z_b, nw, nb, wo, out);
}